// Round 11
// baseline (195.367 us; speedup 1.0000x reference)
//
#include <hip/hip_runtime.h>
#include <math.h>

// CTC forward loss, linear-domain alpha recursion, power-of-2 renorm.
// B=256 -> one block per batch. TERMINAL (R13 verbatim, best verified:
// 194.88 us): producer/consumer wave split.
// Wave 1 (producer): global->LDS staging only. 16-chunk VGPR ring, uniform
//   vmcnt(15) waits, ds_write_b128, lgkmcnt(0) before each barrier.
// Wave 0 (consumer): recursion only. 3 gather ds_read/step (lab0, lab1,
//   blank), uniform lgkmcnt(9) (own queue = reads only), CMT+ALPHA pk-f32,
//   RENORM every 8 steps. No staging in its instruction stream.
// Sync: s_barrier per 8-row group; producer 2 groups ahead on the 32-row
// (4-group) LDS ring. Producer writes slot (g+2)&3 while consumer touches
// slots (g-1..g+1)&3 -> disjoint. Barrier counts: P0 + 128 on both waves.
//
// Session evidence (R8-R18): step time invariant at 93+-4 cy across 7
// structural decompositions (issue count, DS depth, HBM depth, supply
// waves, state split). Floor = serial 1024-step chain; fwd x bwd chain
// halving is algebraically sound but failed correctness twice (bug not
// localizable from pass/fail alone). Banking this verified best.
//
// consumer regs: v12/13 gather addrs, v14 row base, v30:31 allow pair,
//   v96-110 four 3-reg banks (c1,c3,cb; k=t&3), v112-127 alpha state
//   (P=v112:113, Q=v114:115, a4=v116, R=v118:119, CB=v120:121,
//    C13=v122:123, EPS=v124:125, t=v126:127), s90-95 scratch.
// producer regs: v10 global voffset, v11 LDS write addr, v32-95 ring.

#define T_DIM 1024
#define C_DIM 128
#define U_DIM 128
#define LN2F  0.6931471805599453f

#define EPS_LIT "0x33d6bf95"   /* 1e-7f */

// c-multipliers: cb from bank's 3rd reg (VGPR), (c1,c3) from bank pair.
#define CMT(BP,BB) \
  "v_add_f32 v120, v124, " BB "\n\t" \
  "v_mov_b32 v121, v120\n\t" \
  "v_pk_add_f32 v[122:123], " BP ", v[124:125]\n\t"

// packed alpha step (IEEE-identical to R10/R12):
//  t1 = Q+P; t2 = R*L + t1; Q' = t2*(c1,c3)
//  P' = (P+R)*cb ; a4' = (a3+a4)*cb
#define ALPHA \
  "v_mov_b32_dpp v118, v115 wave_shr:1 row_mask:0xf bank_mask:0xf bound_ctrl:0\n\t" \
  "v_mov_b32 v119, v114\n\t" \
  "v_pk_add_f32 v[126:127], v[114:115], v[112:113]\n\t" \
  "v_pk_fma_f32 v[126:127], v[118:119], v[30:31], v[126:127]\n\t" \
  "v_pk_add_f32 v[112:113], v[112:113], v[118:119]\n\t" \
  "v_add_f32 v117, v115, v116\n\t" \
  "v_pk_mul_f32 v[114:115], v[126:127], v[122:123]\n\t" \
  "v_pk_mul_f32 v[112:113], v[112:113], v[120:121]\n\t" \
  "v_mul_f32 v116, v117, v120\n\t"

#define RENORM \
  "v_max_f32 v127, v112, v113\n\t" \
  "v_max_f32 v127, v127, v114\n\t" \
  "v_max_f32 v127, v127, v115\n\t" \
  "v_max_f32 v127, v127, v116\n\t" \
  "s_nop 1\n\t" \
  "v_max_f32_dpp v127, v127, v127 row_ror:8 row_mask:0xf bank_mask:0xf\n\t" \
  "s_nop 1\n\t" \
  "v_max_f32_dpp v127, v127, v127 row_ror:4 row_mask:0xf bank_mask:0xf\n\t" \
  "s_nop 1\n\t" \
  "v_max_f32_dpp v127, v127, v127 row_ror:2 row_mask:0xf bank_mask:0xf\n\t" \
  "s_nop 1\n\t" \
  "v_max_f32_dpp v127, v127, v127 row_ror:1 row_mask:0xf bank_mask:0xf\n\t" \
  "s_nop 1\n\t" \
  "v_readlane_b32 s91, v127, 0\n\t" \
  "v_readlane_b32 s92, v127, 16\n\t" \
  "v_readlane_b32 s93, v127, 32\n\t" \
  "v_readlane_b32 s94, v127, 48\n\t" \
  "s_nop 1\n\t" \
  "s_max_u32 s91, s91, s92\n\t" \
  "s_max_u32 s93, s93, s94\n\t" \
  "s_max_u32 s91, s91, s93\n\t" \
  "s_lshr_b32 s92, s91, 23\n\t" \
  "s_and_b32 s92, s92, 0xff\n\t" \
  "s_sub_u32 s93, 0x126, s92\n\t" \
  "s_min_u32 s93, s93, 0xfe\n\t" \
  "s_lshl_b32 s94, s93, 23\n\t" \
  "s_sub_u32 s95, 0x7f, s93\n\t" \
  "s_add_u32 %[EA], %[EA], s95\n\t" \
  "v_mul_f32 v112, s94, v112\n\t" \
  "v_mul_f32 v113, s94, v113\n\t" \
  "v_mul_f32 v114, s94, v114\n\t" \
  "v_mul_f32 v115, s94, v115\n\t" \
  "v_mul_f32 v116, s94, v116\n\t"

// Variadic indirection so K0..K3 bundles expand before param matching.
#define ST(...) ST_X(__VA_ARGS__)
// Uniform consumer step: wait bank issued 4 steps ago (9 newer reads),
// commit row t, reissue same bank for row t+4.
#define ST_X(B0,B1,B2,BP,ROFF,RBOFF) \
  "s_waitcnt lgkmcnt(9)\n\t" \
  CMT(BP,B2) \
  "ds_read_b32 " B0 ", v12 offset:" ROFF "\n\t" \
  "ds_read_b32 " B1 ", v13 offset:" ROFF "\n\t" \
  "ds_read_b32 " B2 ", v14 offset:" RBOFF "\n\t" \
  ALPHA

// bank bundles (k = t & 3): c1, c3, cb, (c1:c3) pair
#define K0 "v96","v97","v98","v[96:97]"
#define K1 "v100","v101","v102","v[100:101]"
#define K2 "v104","v105","v106","v[104:105]"
#define K3 "v108","v109","v110","v[108:109]"

// ---- producer macros ----
#define PF(SL) \
  "global_load_dwordx4 v[" SL "], v10, %[P]\n\t" \
  "v_add_u32 v10, 0x400, v10\n\t"
// steady write+replenish: 16 in flight -> uniform vmcnt(15)
#define PWL(SL,OFF) \
  "s_waitcnt vmcnt(15)\n\t" \
  "ds_write_b128 v11, v[" SL "] offset:" OFF "\n\t" \
  "global_load_dwordx4 v[" SL "], v10, %[P]\n\t" \
  "v_add_u32 v10, 0x400, v10\n\t"
// tail write (no replenish, descending vmcnt)
#define PW(VC,SL,OFF) \
  "s_waitcnt vmcnt(" VC ")\n\t" \
  "ds_write_b128 v11, v[" SL "] offset:" OFF "\n\t"
// drain writes, then barrier (writes visible to consumer past this point)
#define PBAR \
  "s_waitcnt lgkmcnt(0)\n\t" \
  "s_barrier\n\t"

__global__ __launch_bounds__(128) void ctc_alpha_kernel(
    const int*   __restrict__ y_true,   // (B, U) int32
    const float* __restrict__ y_pred,   // (B, T, C) f32 softmax probs
    float*       __restrict__ out,      // (B, 1) f32
    int B)
{
  __shared__ float4 ldsbuf[1024];       // 16 KB: 32-row x 512 B ring

  const int b = blockIdx.x;
  if (b >= B) return;
  const int tid  = threadIdx.x;
  const int lane = tid & 63;
  const int wid  = tid >> 6;
  const unsigned lds_off = (unsigned)(uintptr_t)(void*)ldsbuf;

  if (wid == 1) {
    // ---------------- producer wave ----------------
    const float* __restrict__ p = y_pred + (size_t)b * (T_DIM * C_DIM);
    const int gvoff  = lane * 16;
    const int wraddr = (int)lds_off + lane * 16;
    asm volatile(
      "s_mov_b32 m0, -1\n\t"
      "v_mov_b32 v10, %[GV]\n\t"
      "v_mov_b32 v11, %[WA]\n\t"
      // 16 prologue loads (chunks 0..15)
      PF("32:35") PF("36:39") PF("40:43") PF("44:47")
      PF("48:51") PF("52:55") PF("56:59") PF("60:63")
      PF("64:67") PF("68:71") PF("72:75") PF("76:79")
      PF("80:83") PF("84:87") PF("88:91") PF("92:95")
      // stage groups 0,1 (chunks 0..7), replenish with chunks 16..23
      PWL("32:35","0")    PWL("36:39","1024") PWL("40:43","2048") PWL("44:47","3072")
      PWL("48:51","4096") PWL("52:55","5120") PWL("56:59","6144") PWL("60:63","7168")
      PBAR                                   // P0: rows 0..15 visible
      // main loop: 30 iters x 4 groups (g=0..119); stage group g+2
      "s_mov_b32 s90, 30\n"
      "LP_%=:\n\t"
      PBAR PWL("64:67","8192")  PWL("68:71","9216")  PWL("72:75","10240") PWL("76:79","11264")
      PBAR PWL("80:83","12288") PWL("84:87","13312") PWL("88:91","14336") PWL("92:95","15360")
      PBAR PWL("32:35","0")     PWL("36:39","1024")  PWL("40:43","2048")  PWL("44:47","3072")
      PBAR PWL("48:51","4096")  PWL("52:55","5120")  PWL("56:59","6144")  PWL("60:63","7168")
      "s_sub_u32 s90, s90, 1\n\t"
      "s_cmp_lg_u32 s90, 0\n\t"
      "s_cbranch_scc1 LP_%=\n\t"
      // g=120,121: last loads (chunks 504..511)
      PBAR PWL("64:67","8192")  PWL("68:71","9216")  PWL("72:75","10240") PWL("76:79","11264")
      PBAR PWL("80:83","12288") PWL("84:87","13312") PWL("88:91","14336") PWL("92:95","15360")
      // g=122..125: write-only, vmcnt descending 15..0
      PBAR PW("15","32:35","0")     PW("14","36:39","1024")  PW("13","40:43","2048")  PW("12","44:47","3072")
      PBAR PW("11","48:51","4096")  PW("10","52:55","5120")  PW("9","56:59","6144")   PW("8","60:63","7168")
      PBAR PW("7","64:67","8192")   PW("6","68:71","9216")   PW("5","72:75","10240")  PW("4","76:79","11264")
      PBAR PW("3","80:83","12288")  PW("2","84:87","13312")  PW("1","88:91","14336")  PW("0","92:95","15360")
      // g=126,127: bare barriers
      PBAR
      PBAR
      :
      : [P]"s"(p), [GV]"v"(gvoff), [WA]"v"(wraddr)
      : "v10","v11",
        "v32","v33","v34","v35","v36","v37","v38","v39","v40","v41","v42","v43",
        "v44","v45","v46","v47","v48","v49","v50","v51","v52","v53","v54","v55",
        "v56","v57","v58","v59","v60","v61","v62","v63","v64","v65","v66","v67",
        "v68","v69","v70","v71","v72","v73","v74","v75","v76","v77","v78","v79",
        "v80","v81","v82","v83","v84","v85","v86","v87","v88","v89","v90","v91",
        "v92","v93","v94","v95",
        "s90","scc","memory");
    return;
  }

  // ---------------- consumer wave ----------------
  const int* __restrict__ yb = y_true + b * U_DIM;
  const int blank = C_DIM - 1;
  const int ylab0 = yb[2 * lane];
  const int ylab1 = yb[2 * lane + 1];
  int yprev = blank;
  if (lane > 0) yprev = yb[2 * lane - 1];
  const float allow1 = (lane > 0 && ylab0 != blank && ylab0 != yprev) ? 1.0f : 0.0f;
  const float allow3 = (ylab1 != blank && ylab1 != ylab0)             ? 1.0f : 0.0f;

  const int rd1 = (int)lds_off + ylab0 * 4;    // gather addr, label0
  const int rd3 = (int)lds_off + ylab1 * 4;    // gather addr, label1
  const int rdb = (int)lds_off;                // row base (blank at +508)

  const float init0 = (lane == 0) ? 1.0f : 0.0f;
  float a3out, a4out;
  int   e_acc = 0;

  asm volatile(
    "s_mov_b32 m0, -1\n\t"
    "v_mov_b32 v12, %[R1]\n\t"
    "v_mov_b32 v13, %[R3]\n\t"
    "v_mov_b32 v14, %[RB]\n\t"
    "v_mov_b32 v30, %[L1]\n\t"
    "v_mov_b32 v31, %[L3]\n\t"
    "v_mov_b32 v112, %[I0]\n\t"
    "v_mov_b32 v113, 0\n\t"
    "v_mov_b32 v114, 0\n\t"
    "v_mov_b32 v115, 0\n\t"
    "v_mov_b32 v116, 0\n\t"
    "v_mov_b32 v124, " EPS_LIT "\n\t"
    "v_mov_b32 v125, " EPS_LIT "\n\t"
    "s_barrier\n\t"                          // P0: rows 0..15 staged
    // prime gathers for rows 0..3 into banks K0..K3 (12 reads)
    "ds_read_b32 v96, v12 offset:0\n\t"
    "ds_read_b32 v97, v13 offset:0\n\t"
    "ds_read_b32 v98, v14 offset:508\n\t"
    "ds_read_b32 v100, v12 offset:512\n\t"
    "ds_read_b32 v101, v13 offset:512\n\t"
    "ds_read_b32 v102, v14 offset:1020\n\t"
    "ds_read_b32 v104, v12 offset:1024\n\t"
    "ds_read_b32 v105, v13 offset:1024\n\t"
    "ds_read_b32 v106, v14 offset:1532\n\t"
    "ds_read_b32 v108, v12 offset:1536\n\t"
    "ds_read_b32 v109, v13 offset:1536\n\t"
    "ds_read_b32 v110, v14 offset:2044\n\t"
    // main loop: 32 iters x 32 steps; barrier per 8-row group
    "s_mov_b32 s90, 32\n"
    "LM_%=:\n\t"
    "s_barrier\n\t"
    ST(K0,"2048","2556")   ST(K1,"2560","3068")   ST(K2,"3072","3580")   ST(K3,"3584","4092")
    ST(K0,"4096","4604")   ST(K1,"4608","5116")   ST(K2,"5120","5628")   ST(K3,"5632","6140")
    RENORM
    "s_barrier\n\t"
    ST(K0,"6144","6652")   ST(K1,"6656","7164")   ST(K2,"7168","7676")   ST(K3,"7680","8188")
    ST(K0,"8192","8700")   ST(K1,"8704","9212")   ST(K2,"9216","9724")   ST(K3,"9728","10236")
    RENORM
    "s_barrier\n\t"
    ST(K0,"10240","10748") ST(K1,"10752","11260") ST(K2,"11264","11772") ST(K3,"11776","12284")
    ST(K0,"12288","12796") ST(K1,"12800","13308") ST(K2,"13312","13820") ST(K3,"13824","14332")
    RENORM
    "s_barrier\n\t"
    ST(K0,"14336","14844") ST(K1,"14848","15356") ST(K2,"15360","15868") ST(K3,"15872","16380")
    ST(K0,"0","508")       ST(K1,"512","1020")    ST(K2,"1024","1532")   ST(K3,"1536","2044")
    RENORM
    "s_sub_u32 s90, s90, 1\n\t"
    "s_cmp_lg_u32 s90, 0\n\t"
    "s_cbranch_scc1 LM_%=\n\t"
    "s_waitcnt lgkmcnt(0)\n\t"
    "v_mov_b32 %[O3], v115\n\t"
    "v_mov_b32 %[O4], v116\n\t"
    : [O3]"=v"(a3out), [O4]"=v"(a4out), [EA]"+s"(e_acc)
    : [R1]"v"(rd1), [R3]"v"(rd3), [RB]"v"(rdb),
      [L1]"v"(allow1), [L3]"v"(allow3), [I0]"v"(init0)
    : "v12","v13","v14","v30","v31",
      "v96","v97","v98","v100","v101","v102",
      "v104","v105","v106","v108","v109","v110",
      "v112","v113","v114","v115","v116","v117","v118","v119","v120","v121",
      "v122","v123","v124","v125","v126","v127",
      "s90","s91","s92","s93","s94","s95","scc","memory");

  if (lane == 63) {
    float s = a3out + a4out;           // alpha[255] + alpha[256]
    s = fmaxf(s, 1e-37f);
    float ll = logf(s) + (float)e_acc * LN2F;
    out[b] = -ll;
  }
}

extern "C" void kernel_launch(void* const* d_in, const int* in_sizes, int n_in,
                              void* d_out, int out_size, void* d_ws, size_t ws_size,
                              hipStream_t stream) {
  const int*   y_true = (const int*)d_in[0];
  const float* y_pred = (const float*)d_in[1];
  float*       out    = (float*)d_out;
  const int B = in_sizes[0] / U_DIM;   // 256
  ctc_alpha_kernel<<<dim3(B), dim3(128), 0, stream>>>(y_true, y_pred, out, B);
}